// Round 7
// baseline (89.200 us; speedup 1.0000x reference)
//
#include <hip/hip_runtime.h>
#include <stdint.h>

// Problem constants (LSHSoftmax): B=1024, D=512, N=500000, S=32768
#define B_DIM 1024
#define D_DIM 512
#define S_DIM 32768

typedef __attribute__((ext_vector_type(8))) short bf16x8;   // 8 bf16 = 4 VGPRs
typedef __attribute__((ext_vector_type(4))) float f32x4;
typedef __attribute__((ext_vector_type(8))) unsigned short u16x8;

#define AS1 __attribute__((address_space(1)))
#define AS3 __attribute__((address_space(3)))

__device__ __forceinline__ unsigned short f2bf(float f) {
  union { float f; uint32_t u; } x; x.f = f;
  uint32_t r = x.u + 0x7fffu + ((x.u >> 16) & 1u);   // RNE
  return (unsigned short)(r >> 16);
}

// v_cvt_pk_bf16_f32: D.lo16 = bf16(a), D.hi16 = bf16(b) — 1 inst for 2 elts.
__device__ __forceinline__ uint32_t cvtpk(float a, float b) {
  uint32_t r;
  asm("v_cvt_pk_bf16_f32 %0, %1, %2" : "=v"(r) : "v"(a), "v"(b));
  return r;
}

// Convert inputs A f32 -> bf16 (2 MiB read, 1 MiB write; reused by all 256 bn).
__global__ __launch_bounds__(256) void conv_a(const float* __restrict__ A,
                                              unsigned short* __restrict__ Ab) {
  int gid = blockIdx.x * 256 + threadIdx.x;
  const float* src = A + (size_t)gid * 8;
  float4 v0 = *(const float4*)src;
  float4 v1 = *(const float4*)(src + 4);
  u16x8 o;
  o[0] = f2bf(v0.x); o[1] = f2bf(v0.y); o[2] = f2bf(v0.z); o[3] = f2bf(v0.w);
  o[4] = f2bf(v1.x); o[5] = f2bf(v1.y); o[6] = f2bf(v1.z); o[7] = f2bf(v1.w);
  *(u16x8*)(Ab + (size_t)gid * 8) = o;
}

// ---------------------------------------------------------------------------
// Fused gather+GEMM: C[m,n] = sum_k Ab[m,k] * W[ids[n],k] + bias[ids[n]]
// 128x128 tile, BK=64, 8 waves (2r x 4c, 64x32 out each), 2 LDS buffers
// (64 KiB total -> 2 blocks/CU), one barrier per K-iter.
// A: global_load_lds (bf16, pre-swizzled source). B: reg-staged gather from
// W (f32) issued at TOP of iter kt for tile kt+1, converted via
// v_cvt_pk_bf16_f32 (8 insts) + 2 swizzled ds_write_b128 AFTER the MFMA
// cluster (T14 issue-early/write-late; HBM latency hides under ds_read+MFMA).
// XOR swizzle byte^((row&7)<<4) on both write and read sides (involution).
// ---------------------------------------------------------------------------
#define BM 128
#define BN 128
#define BK 64
#define NKT (D_DIM / BK)           // 8 K-tiles
#define A_BYTES (BM * BK * 2)      // 16384
#define B_BYTES (BN * BK * 2)      // 16384
#define BUFBYTES (A_BYTES + B_BYTES) // 32768; x2 buffers = 64 KiB

__global__ __launch_bounds__(512, 4) void gemm_fused(const unsigned short* __restrict__ Ab,
                                                     const float* __restrict__ W,
                                                     const float* __restrict__ bias,
                                                     const int* __restrict__ ids,
                                                     float* __restrict__ out) {
  __shared__ __attribute__((aligned(16))) char lds[2 * BUFBYTES];

  const int tid = threadIdx.x;
  const int lane = tid & 63;
  const int w = tid >> 6;          // wave 0..7
  const int wr = w >> 2;           // wave row 0..1 (64 rows each)
  const int wc = w & 3;            // wave col 0..3 (32 cols each)
  const int lq = lane >> 4;        // 0..3
  const int l16 = lane & 15;

  // XCD swizzle: 2048 blocks, 8 XCDs, 256 contiguous ids per XCD; bm fastest
  // so 8 dispatch-adjacent blocks share one W panel (gather reads L2-hit).
  int id = ((blockIdx.x & 7) << 8) | (blockIdx.x >> 3);
  const int bm = id & 7;           // 8 row tiles
  const int bn = id >> 3;          // 256 col tiles
  const int m0 = bm * BM;
  const int n0 = bn * BN;

  // B-gather role: thread covers tile-row (=C col) srow = tid>>2, k-seg
  // sseg = tid&3 (16 consecutive f32). One id load per thread, L1-broadcast.
  const int srow = tid >> 2;
  const int sseg = tid & 3;
  const int myid = ids[n0 + srow];
  const float* wbase = W + (size_t)myid * D_DIM + sseg * 16;
  const int sbyte = srow * 128 + sseg * 32;     // logical LDS byte
  const int sswz = (srow & 7) << 4;

  f32x4 acc[4][2];
#pragma unroll
  for (int m = 0; m < 4; ++m)
#pragma unroll
    for (int n = 0; n < 2; ++n)
      acc[m][n] = (f32x4)0.0f;

  // A staging: linear LDS dest (wave-uniform), inverse-swizzled source.
  auto stageA = [&](int kt) {
    char* ldsA = lds + (kt & 1) * BUFBYTES;
#pragma unroll
    for (int j = 0; j < 2; ++j) {               // 16 KB = 8 waves x 2 x 1KB
      const int Pb = j * 8192 + w * 1024;       // wave-uniform
      const int P = Pb + lane * 16;
      const int L = P ^ (((P >> 7) & 7) << 4);  // logical byte in tile
      const char* srcA = (const char*)Ab +
          (size_t)(m0 + (L >> 7)) * (D_DIM * 2) + kt * (BK * 2) + (L & 127);
      __builtin_amdgcn_global_load_lds((const AS1 void*)srcA,
                                       (AS3 void*)(ldsA + Pb), 16, 0, 0);
    }
  };

  float4 q0, q1, q2, q3;                        // B gather regs (one set)
  auto loadB = [&](int kt) {                    // 4 x global f32x4
    const float* p = wbase + kt * BK;
    q0 = *(const float4*)(p + 0);
    q1 = *(const float4*)(p + 4);
    q2 = *(const float4*)(p + 8);
    q3 = *(const float4*)(p + 12);
  };
  auto writeB = [&](int kt) {                   // cvt_pk + 2 swizzled b128
    char* bb = lds + (kt & 1) * BUFBYTES + A_BYTES;
    int4 w0, w1;
    w0.x = cvtpk(q0.x, q0.y); w0.y = cvtpk(q0.z, q0.w);
    w0.z = cvtpk(q1.x, q1.y); w0.w = cvtpk(q1.z, q1.w);
    w1.x = cvtpk(q2.x, q2.y); w1.y = cvtpk(q2.z, q2.w);
    w1.z = cvtpk(q3.x, q3.y); w1.w = cvtpk(q3.z, q3.w);
    *(int4*)(bb + (sbyte ^ sswz)) = w0;
    *(int4*)(bb + ((sbyte + 16) ^ sswz)) = w1;
  };

  // ---- Prologue: tile 0 ----
  loadB(0);
  stageA(0);
  asm volatile("s_waitcnt vmcnt(2)" ::: "memory");   // B0 regs landed
  writeB(0);
  asm volatile("s_waitcnt vmcnt(0)" ::: "memory");   // A0 in LDS
  asm volatile("s_waitcnt lgkmcnt(0)" ::: "memory"); // B0 writes visible
  __builtin_amdgcn_s_barrier();

  const int swz = (l16 & 7) << 4;   // fragment-row swizzle (row&7 == l16&7)

#pragma unroll
  for (int kt = 0; kt < NKT; ++kt) {
    __builtin_amdgcn_sched_barrier(0);
    // issue next tile's loads first (T14): HBM latency hides under this
    // iter's ds_read + MFMA. Buffer (kt+1)&1 was released at barrier(kt-1).
    if (kt < NKT - 1) {
      loadB(kt + 1);
      stageA(kt + 1);
    }
    __builtin_amdgcn_sched_barrier(0);

    const char* ldsA = lds + (kt & 1) * BUFBYTES;
    const char* ldsB = ldsA + A_BYTES;

#pragma unroll
    for (int kk = 0; kk < 2; ++kk) {
      bf16x8 af[4], bv[2];
#pragma unroll
      for (int m = 0; m < 4; ++m) {
        const int row = wr * 64 + m * 16 + l16;
        const int byte = row * 128 + (kk * 32 + lq * 8) * 2;
        af[m] = *(const bf16x8*)(ldsA + (byte ^ swz));
      }
#pragma unroll
      for (int n = 0; n < 2; ++n) {
        const int row = wc * 32 + n * 16 + l16;
        const int byte = row * 128 + (kk * 32 + lq * 8) * 2;
        bv[n] = *(const bf16x8*)(ldsB + (byte ^ swz));
      }
      __builtin_amdgcn_s_setprio(1);
#pragma unroll
      for (int m = 0; m < 4; ++m)
#pragma unroll
        for (int n = 0; n < 2; ++n)
          acc[m][n] = __builtin_amdgcn_mfma_f32_16x16x32_bf16(af[m], bv[n],
                                                              acc[m][n], 0, 0, 0);
      __builtin_amdgcn_s_setprio(0);
    }
    __builtin_amdgcn_sched_barrier(0);

    if (kt < NKT - 1) {
      // outstanding (oldest->newest): B(kt+1) x4, A(kt+1) x2.
      asm volatile("s_waitcnt vmcnt(2)" ::: "memory");   // B regs landed
      writeB(kt + 1);                                    // into buf (kt+1)&1
      __builtin_amdgcn_sched_barrier(0);
      asm volatile("s_waitcnt vmcnt(0)" ::: "memory");   // A(kt+1) in LDS
      asm volatile("s_waitcnt lgkmcnt(0)" ::: "memory"); // writes visible
      __builtin_amdgcn_s_barrier();                      // release/publish
    }
  }

  // ---- Epilogue: C[row][col] = acc + bias[ids[col]] (col=l16, row=lq*4+r) --
  const int lrow = lq * 4;
#pragma unroll
  for (int n = 0; n < 2; ++n) {
    const int col = n0 + wc * 32 + n * 16 + l16;
    const float bvv = bias[ids[col]];
#pragma unroll
    for (int m = 0; m < 4; ++m) {
      const int rbase = m0 + wr * 64 + m * 16 + lrow;
#pragma unroll
      for (int r = 0; r < 4; ++r) {
        out[(size_t)(rbase + r) * S_DIM + col] = acc[m][n][r] + bvv;
      }
    }
  }
}

extern "C" void kernel_launch(void* const* d_in, const int* in_sizes, int n_in,
                              void* d_out, int out_size, void* d_ws, size_t ws_size,
                              hipStream_t stream) {
  const float* inp  = (const float*)d_in[0];   // [B, D] f32
  const float* W    = (const float*)d_in[1];   // [N, D] f32
  const float* bias = (const float*)d_in[2];   // [N] f32
  const int*   ids  = (const int*)d_in[3];     // [S] int32
  float* out = (float*)d_out;                  // [B, S] f32

  unsigned short* Ab = (unsigned short*)d_ws;  // [B, D] bf16 (1 MiB)

  conv_a<<<(B_DIM * D_DIM / 8) / 256, 256, 0, stream>>>(inp, Ab);

  dim3 grid((B_DIM / BM) * (S_DIM / BN));      // 8 * 256 = 2048 blocks
  gemm_fused<<<grid, 512, 0, stream>>>(Ab, W, bias, ids, out);
}

// Round 8
// 73.000 us; speedup vs baseline: 1.2219x; 1.2219x over previous
//
#include <hip/hip_runtime.h>
#include <stdint.h>

// Problem constants (LSHSoftmax): B=1024, D=512, N=500000, S=32768
#define B_DIM 1024
#define D_DIM 512
#define S_DIM 32768

typedef __attribute__((ext_vector_type(8))) short bf16x8;   // 8 bf16 = 4 VGPRs
typedef __attribute__((ext_vector_type(4))) float f32x4;
typedef __attribute__((ext_vector_type(8))) unsigned short u16x8;

#define AS1 __attribute__((address_space(1)))
#define AS3 __attribute__((address_space(3)))

__device__ __forceinline__ unsigned short f2bf(float f) {
  union { float f; uint32_t u; } x; x.f = f;
  uint32_t r = x.u + 0x7fffu + ((x.u >> 16) & 1u);   // RNE
  return (unsigned short)(r >> 16);
}

// Fused prep: blocks [0, 8192) gather+convert W rows by ids; [8192, 8448) conv A.
#define GATHER_BLOCKS (S_DIM / 4)              // 8192
#define CONV_BLOCKS (B_DIM * D_DIM / 8 / 256)  // 256

__global__ __launch_bounds__(256) void prep(const float* __restrict__ W,
                                            const float* __restrict__ bias,
                                            const int* __restrict__ ids,
                                            const float* __restrict__ A,
                                            unsigned short* __restrict__ Wg,
                                            unsigned short* __restrict__ Ab,
                                            float* __restrict__ bg) {
  if (blockIdx.x < GATHER_BLOCKS) {
    int gid = blockIdx.x * 256 + threadIdx.x;
    int s = gid >> 6;
    int c = (gid & 63) * 8;
    int sid = ids[s];
    const float* src = W + (size_t)sid * D_DIM + c;
    float4 v0 = *(const float4*)src;
    float4 v1 = *(const float4*)(src + 4);
    u16x8 o;
    o[0] = f2bf(v0.x); o[1] = f2bf(v0.y); o[2] = f2bf(v0.z); o[3] = f2bf(v0.w);
    o[4] = f2bf(v1.x); o[5] = f2bf(v1.y); o[6] = f2bf(v1.z); o[7] = f2bf(v1.w);
    *(u16x8*)(Wg + (size_t)s * D_DIM + c) = o;
    if ((gid & 63) == 0) bg[s] = bias[sid];
  } else {
    int gid = (blockIdx.x - GATHER_BLOCKS) * 256 + threadIdx.x;
    const float* src = A + (size_t)gid * 8;
    float4 v0 = *(const float4*)src;
    float4 v1 = *(const float4*)(src + 4);
    u16x8 o;
    o[0] = f2bf(v0.x); o[1] = f2bf(v0.y); o[2] = f2bf(v0.z); o[3] = f2bf(v0.w);
    o[4] = f2bf(v1.x); o[5] = f2bf(v1.y); o[6] = f2bf(v1.z); o[7] = f2bf(v1.w);
    *(u16x8*)(Ab + (size_t)gid * 8) = o;
  }
}

// ---------------------------------------------------------------------------
// GEMM: C[m,n] = sum_k Ab[m,k]*Wg[n,k] + bg[n]
// 128x128 tile, BK=32 (16 K-iters), 8 waves (2M x 4N, 64x32 out each),
// 3 LDS buffers x 16 KB = 48 KB, depth-2 prefetch with counted vmcnt (never
// drain in loop), raw barriers, setprio, XCD swizzle. __launch_bounds__(512,6)
// caps VGPR at 85 -> target 3 blocks/CU (24 waves) so staggered blocks smooth
// the epilogue write bursts and hide per-iter stage latency.
// LDS layout: 64B rows paired into 128B lines, slot-XOR swizzle
//   phys = (r>>1)*128 + (((r&1)*64 + cb) ^ (((r>>1)&7)<<4))
// -> ds_read_b128 is 2-way per 16-lane group (free, m136); gload_lds dest
// stays linear, source inverse-permuted.
// ---------------------------------------------------------------------------
#define BM 128
#define BN 128
#define BK 32
#define NKT (D_DIM / BK)            // 16 K-tiles
#define REGB 8192                   // bytes per A (or B) region per buffer
#define BUFBYTES (2 * REGB)         // 16384; 3 buffers = 48 KiB

__global__ __launch_bounds__(512, 6) void gemm_bias(const unsigned short* __restrict__ Ab,
                                                    const unsigned short* __restrict__ Wg,
                                                    const float* __restrict__ bg,
                                                    float* __restrict__ out) {
  __shared__ __attribute__((aligned(16))) char lds[3 * BUFBYTES];

  const int tid = threadIdx.x;
  const int lane = tid & 63;
  const int w = tid >> 6;          // wave 0..7
  const int wr = w >> 2;           // wave row 0..1 (64 rows each)
  const int wc = w & 3;            // wave col 0..3 (32 cols each)
  const int lq = lane >> 4;        // 0..3
  const int l16 = lane & 15;

  // XCD swizzle: 2048 blocks, 8 XCDs, 256 contiguous ids per XCD; bm fastest
  // so 8 dispatch-adjacent blocks on one XCD share the same B panel.
  int id = ((blockIdx.x & 7) << 8) | (blockIdx.x >> 3);
  const int m0 = (id & 7) * BM;
  const int n0 = (id >> 3) * BN;

  f32x4 acc[4][2];
#pragma unroll
  for (int m = 0; m < 4; ++m)
#pragma unroll
    for (int n = 0; n < 2; ++n)
      acc[m][n] = (f32x4)0.0f;

  // Staging: thread t fills physical 16B slot t. Inverse of the read swizzle:
  // p = t>>3, slot_log = (t&7) ^ (p&7), r = 2p + (slot_log>>2),
  // cb = (slot_log&3)*16.  (Verified involution: phys == t*16.)
  const int sp = tid >> 3;
  const int ssl = (tid & 7) ^ (sp & 7);
  const int srow = (sp << 1) + (ssl >> 2);
  const int scb = (ssl & 3) << 4;
  const char* sA0 = (const char*)Ab + (size_t)(m0 + srow) * (D_DIM * 2) + scb;
  const char* sB0 = (const char*)Wg + (size_t)(n0 + srow) * (D_DIM * 2) + scb;

  auto stage = [&](int kt) {
    char* base = lds + (kt % 3) * BUFBYTES + w * 1024;
    __builtin_amdgcn_global_load_lds((const AS1 void*)(sA0 + kt * (BK * 2)),
                                     (AS3 void*)base, 16, 0, 0);
    __builtin_amdgcn_global_load_lds((const AS1 void*)(sB0 + kt * (BK * 2)),
                                     (AS3 void*)(base + REGB), 16, 0, 0);
  };

  // Precompute fragment LDS offsets (kt-independent).
  int aoff[4], boff[2];
#pragma unroll
  for (int m = 0; m < 4; ++m) {
    const int r = wr * 64 + m * 16 + l16;
    aoff[m] = (r >> 1) * 128 + ((((r & 1) << 6) + (lq << 4)) ^ (((r >> 1) & 7) << 4));
  }
#pragma unroll
  for (int n = 0; n < 2; ++n) {
    const int r = wc * 32 + n * 16 + l16;
    boff[n] = REGB + (r >> 1) * 128 + ((((r & 1) << 6) + (lq << 4)) ^ (((r >> 1) & 7) << 4));
  }

  // ---- Prologue: tiles 0,1 in flight (4 loads/wave) ----
  stage(0);
  stage(1);

  for (int kt = 0; kt < NKT; ++kt) {
    __builtin_amdgcn_sched_barrier(0);
    if (kt < NKT - 2) {
      stage(kt + 2);                 // buffer (kt+2)%3 == (kt-1)%3, released
                                     // at iter kt-1's trailing barrier.
      __builtin_amdgcn_sched_barrier(0);
      asm volatile("s_waitcnt vmcnt(4)" ::: "memory");   // tile kt landed
    } else if (kt == NKT - 2) {
      asm volatile("s_waitcnt vmcnt(2)" ::: "memory");
    } else {
      asm volatile("s_waitcnt vmcnt(0)" ::: "memory");
    }
    __builtin_amdgcn_s_barrier();    // raw barrier: no vmcnt(0) drain
    __builtin_amdgcn_sched_barrier(0);

    const char* bufb = lds + (kt % 3) * BUFBYTES;
    bf16x8 af[4], bv[2];
#pragma unroll
    for (int m = 0; m < 4; ++m) af[m] = *(const bf16x8*)(bufb + aoff[m]);
#pragma unroll
    for (int n = 0; n < 2; ++n) bv[n] = *(const bf16x8*)(bufb + boff[n]);

    __builtin_amdgcn_s_setprio(1);
#pragma unroll
    for (int m = 0; m < 4; ++m)
#pragma unroll
      for (int n = 0; n < 2; ++n)
        acc[m][n] = __builtin_amdgcn_mfma_f32_16x16x32_bf16(af[m], bv[n],
                                                            acc[m][n], 0, 0, 0);
    __builtin_amdgcn_s_setprio(0);

    __builtin_amdgcn_sched_barrier(0);
    __builtin_amdgcn_s_barrier();    // all waves done with buf kt%3 before
                                     // stage(kt+3) (next iter) overwrites it
  }

  // ---- Epilogue: C[row][col] = acc + bias (col = l16, row = lq*4 + r) ----
  const int lrow = lq * 4;
#pragma unroll
  for (int n = 0; n < 2; ++n) {
    const int col = n0 + wc * 32 + n * 16 + l16;
    const float bvv = bg[col];
#pragma unroll
    for (int m = 0; m < 4; ++m) {
      const int rbase = m0 + wr * 64 + m * 16 + lrow;
#pragma unroll
      for (int r = 0; r < 4; ++r) {
        out[(size_t)(rbase + r) * S_DIM + col] = acc[m][n][r] + bvv;
      }
    }
  }
}

extern "C" void kernel_launch(void* const* d_in, const int* in_sizes, int n_in,
                              void* d_out, int out_size, void* d_ws, size_t ws_size,
                              hipStream_t stream) {
  const float* inp  = (const float*)d_in[0];   // [B, D] f32
  const float* W    = (const float*)d_in[1];   // [N, D] f32
  const float* bias = (const float*)d_in[2];   // [N] f32
  const int*   ids  = (const int*)d_in[3];     // [S] int32
  float* out = (float*)d_out;                  // [B, S] f32

  unsigned short* Wg = (unsigned short*)d_ws;                       // [S,D] bf16 (32 MiB)
  unsigned short* Ab = (unsigned short*)((char*)d_ws +
                        (size_t)S_DIM * D_DIM * 2);                 // [B,D] bf16 (1 MiB)
  float* bg = (float*)((char*)d_ws +
                        (size_t)S_DIM * D_DIM * 2 + (size_t)B_DIM * D_DIM * 2); // [S] f32

  prep<<<GATHER_BLOCKS + CONV_BLOCKS, 256, 0, stream>>>(W, bias, ids, inp, Wg, Ab, bg);

  dim3 grid((B_DIM / BM) * (S_DIM / BN));   // 8 * 256 = 2048 blocks
  gemm_bias<<<grid, 512, 0, stream>>>(Ab, Wg, bg, out);
}